// Round 1
// baseline (226.804 us; speedup 1.0000x reference)
//
#include <hip/hip_runtime.h>
#include <hip/hip_bf16.h>

// Problem dims (fixed by reference): B=2,S=1024 -> T=2048 tokens
#define T_TOK 2048
#define DIM   2048   // D
#define FFN   1024   // F
#define NE    8      // experts
// top_k = 2 hardcoded

typedef __attribute__((ext_vector_type(8))) short bf16x8;
typedef __attribute__((ext_vector_type(4))) float f32x4;

__device__ __forceinline__ unsigned short f2bf(float f) {
  __hip_bfloat16 h = __float2bfloat16(f);
  return __builtin_bit_cast(unsigned short, h);
}

__device__ __forceinline__ void gload_lds16(const unsigned short* g, unsigned short* l) {
  __builtin_amdgcn_global_load_lds(
      (const __attribute__((address_space(1))) void*)g,
      (__attribute__((address_space(3))) void*)l, 16, 0, 0);
}

// ---------------- fp32 -> bf16 conversion (vectorized) ----------------
__global__ void cvt_f32_to_bf16(const float* __restrict__ in,
                                unsigned short* __restrict__ out, int n4) {
  int i = blockIdx.x * blockDim.x + threadIdx.x;
  int stride = gridDim.x * blockDim.x;
  for (; i < n4; i += stride) {
    float4 v = reinterpret_cast<const float4*>(in)[i];
    ushort4 o;
    o.x = f2bf(v.x); o.y = f2bf(v.y); o.z = f2bf(v.z); o.w = f2bf(v.w);
    reinterpret_cast<ushort4*>(out)[i] = o;
  }
}

// ---------------- router: logits + top2 + softmax gates ----------------
// one wave per token; fp32 exact-ish (top-k ordering must match reference)
__global__ __launch_bounds__(256) void router_topk(
    const float* __restrict__ x, const float* __restrict__ wr,
    int* __restrict__ top_i, float* __restrict__ top_g) {
  int t = blockIdx.x * 4 + (threadIdx.x >> 6);
  int lane = threadIdx.x & 63;
  const float4* xr = reinterpret_cast<const float4*>(x) + (size_t)t * (DIM / 4);
  const float4* wrv = reinterpret_cast<const float4*>(wr);
  float acc[NE];
#pragma unroll
  for (int e = 0; e < NE; ++e) acc[e] = 0.f;
#pragma unroll
  for (int it = 0; it < DIM / 4 / 64; ++it) {
    int d4 = it * 64 + lane;
    float4 xv = xr[d4];
#pragma unroll
    for (int e = 0; e < NE; ++e) {
      float4 wv = wrv[e * (DIM / 4) + d4];
      acc[e] += xv.x * wv.x + xv.y * wv.y + xv.z * wv.z + xv.w * wv.w;
    }
  }
#pragma unroll
  for (int off = 32; off > 0; off >>= 1) {
#pragma unroll
    for (int e = 0; e < NE; ++e) acc[e] += __shfl_xor(acc[e], off, 64);
  }
  if (lane == 0) {
    // top-2, ties -> lower index (matches jax.lax.top_k)
    int i0 = 0; float m0 = acc[0];
#pragma unroll
    for (int e = 1; e < NE; ++e) if (acc[e] > m0) { m0 = acc[e]; i0 = e; }
    int i1 = -1; float m1 = -3.4e38f;
#pragma unroll
    for (int e = 0; e < NE; ++e) if (e != i0 && acc[e] > m1) { m1 = acc[e]; i1 = e; }
    float tv = expf(m1 - m0);
    float den = 1.f + tv;
    top_i[t * 2 + 0] = i0; top_i[t * 2 + 1] = i1;
    top_g[t * 2 + 0] = 1.f / den; top_g[t * 2 + 1] = tv / den;
  }
}

// ---------------- count per expert + exclusive prefix offsets ----------------
__global__ void count_offsets(const int* __restrict__ top_i,
                              int* __restrict__ offs, int* __restrict__ cursor) {
  __shared__ int cnt[NE];
  if (threadIdx.x < NE) cnt[threadIdx.x] = 0;
  __syncthreads();
  for (int i = threadIdx.x; i < T_TOK * 2; i += blockDim.x) atomicAdd(&cnt[top_i[i]], 1);
  __syncthreads();
  if (threadIdx.x == 0) {
    int s = 0;
    for (int e = 0; e < NE; ++e) { offs[e] = s; cursor[e] = s; s += cnt[e]; }
    offs[NE] = s;  // == 2*T_TOK
  }
}

// ---------------- scatter tokens into compact per-expert lists ----------------
__global__ void scatter_tokens(const int* __restrict__ top_i, const float* __restrict__ top_g,
                               int* __restrict__ cursor, int* __restrict__ tok_list,
                               float* __restrict__ gate_lst, int* __restrict__ slot_lst) {
  int t = blockIdx.x * blockDim.x + threadIdx.x;
  if (t >= T_TOK) return;
#pragma unroll
  for (int s = 0; s < 2; ++s) {
    int e = top_i[t * 2 + s];
    int p = atomicAdd(&cursor[e], 1);
    tok_list[p] = t;
    gate_lst[p] = top_g[t * 2 + s];
    slot_lst[p] = s;
  }
}

// ---------------- fused gate+up grouped GEMM -> h = silu(g)*u ----------------
// per expert e: C[m][n] = sum_k A[m][k]*B[n][k], A = gathered x rows (bf16),
// B = w_gate[e]/w_up[e] ([F][D] row-major = BT layout). 128x128 tile, BK=32.
__global__ __launch_bounds__(256, 2) void gateup_gemm(
    const unsigned short* __restrict__ xb, const unsigned short* __restrict__ wgb,
    const unsigned short* __restrict__ wub, const int* __restrict__ tok_list,
    const int* __restrict__ offs, unsigned short* __restrict__ hbuf) {
  const int e = blockIdx.z;
  const int row0 = offs[e];
  const int n_e = offs[e + 1] - row0;
  const int mt = blockIdx.y;
  if (mt * 128 >= n_e) return;
  const int nt = blockIdx.x;

  __shared__ unsigned short As[128 * 32];
  __shared__ unsigned short Bg[128 * 32];
  __shared__ unsigned short Bu[128 * 32];

  const int tid = threadIdx.x;
  const int wid = tid >> 6;
  const int lane = tid & 63;

  // staging geometry: per wave two 1KB chunks (16 rows x 64B each), lane -> row l/4, 16B chunk l%4
  const int sr0 = wid * 32 + (lane >> 2);
  const int sr1 = sr0 + 16;
  const int sc = (lane & 3) * 8;

  int ar0 = mt * 128 + sr0; if (ar0 >= n_e) ar0 = n_e - 1;
  int ar1 = mt * 128 + sr1; if (ar1 >= n_e) ar1 = n_e - 1;
  const unsigned short* ga0 = xb + (size_t)tok_list[row0 + ar0] * DIM + sc;
  const unsigned short* ga1 = xb + (size_t)tok_list[row0 + ar1] * DIM + sc;

  const size_t wbase = (size_t)e * FFN * DIM + (size_t)(nt * 128) * DIM;
  const unsigned short* gg0 = wgb + wbase + (size_t)sr0 * DIM + sc;
  const unsigned short* gg1 = wgb + wbase + (size_t)sr1 * DIM + sc;
  const unsigned short* gu0 = wub + wbase + (size_t)sr0 * DIM + sc;
  const unsigned short* gu1 = wub + wbase + (size_t)sr1 * DIM + sc;

  unsigned short* lA0 = &As[(wid * 32) * 32];
  unsigned short* lA1 = &As[(wid * 32 + 16) * 32];
  unsigned short* lG0 = &Bg[(wid * 32) * 32];
  unsigned short* lG1 = &Bg[(wid * 32 + 16) * 32];
  unsigned short* lU0 = &Bu[(wid * 32) * 32];
  unsigned short* lU1 = &Bu[(wid * 32 + 16) * 32];

  f32x4 accg[4][4];
  f32x4 accu[4][4];
#pragma unroll
  for (int i = 0; i < 4; ++i)
#pragma unroll
    for (int j = 0; j < 4; ++j) {
      accg[i][j] = (f32x4){0.f, 0.f, 0.f, 0.f};
      accu[i][j] = (f32x4){0.f, 0.f, 0.f, 0.f};
    }

  const int wrow = (wid >> 1) * 64;
  const int wcol = (wid & 1) * 64;
  const int frow = lane & 15;
  const int fk = (lane >> 4) * 8;

  for (int k0 = 0; k0 < DIM; k0 += 32) {
    gload_lds16(ga0 + k0, lA0);
    gload_lds16(ga1 + k0, lA1);
    gload_lds16(gg0 + k0, lG0);
    gload_lds16(gg1 + k0, lG1);
    gload_lds16(gu0 + k0, lU0);
    gload_lds16(gu1 + k0, lU1);
    __syncthreads();
    bf16x8 af[4], bg[4], bu[4];
#pragma unroll
    for (int i = 0; i < 4; ++i)
      af[i] = *reinterpret_cast<const bf16x8*>(&As[(wrow + i * 16 + frow) * 32 + fk]);
#pragma unroll
    for (int j = 0; j < 4; ++j) {
      bg[j] = *reinterpret_cast<const bf16x8*>(&Bg[(wcol + j * 16 + frow) * 32 + fk]);
      bu[j] = *reinterpret_cast<const bf16x8*>(&Bu[(wcol + j * 16 + frow) * 32 + fk]);
    }
#pragma unroll
    for (int i = 0; i < 4; ++i)
#pragma unroll
      for (int j = 0; j < 4; ++j) {
        accg[i][j] = __builtin_amdgcn_mfma_f32_16x16x32_bf16(af[i], bg[j], accg[i][j], 0, 0, 0);
        accu[i][j] = __builtin_amdgcn_mfma_f32_16x16x32_bf16(af[i], bu[j], accu[i][j], 0, 0, 0);
      }
    __syncthreads();
  }

  // epilogue: h = silu(g)*u -> bf16, row r of compact expert block
#pragma unroll
  for (int i = 0; i < 4; ++i) {
#pragma unroll
    for (int jj = 0; jj < 4; ++jj) {
      int r = mt * 128 + wrow + i * 16 + (lane >> 4) * 4 + jj;
      if (r < n_e) {
#pragma unroll
        for (int j = 0; j < 4; ++j) {
          float g = accg[i][j][jj];
          float u = accu[i][j][jj];
          float h = (g / (1.f + __expf(-g))) * u;
          int f = nt * 128 + wcol + j * 16 + (lane & 15);
          hbuf[(size_t)(row0 + r) * FFN + f] = f2bf(h);
        }
      }
    }
  }
}

// ---------------- grouped down GEMM -> yslots[slot][token][d] = gate*val ----------------
__global__ __launch_bounds__(256, 2) void down_gemm(
    const unsigned short* __restrict__ hbuf, const unsigned short* __restrict__ wdb,
    const int* __restrict__ tok_list, const float* __restrict__ gate_lst,
    const int* __restrict__ slot_lst, const int* __restrict__ offs,
    float* __restrict__ yslots) {
  const int e = blockIdx.z;
  const int row0 = offs[e];
  const int n_e = offs[e + 1] - row0;
  const int mt = blockIdx.y;
  if (mt * 128 >= n_e) return;
  const int nt = blockIdx.x;  // D tile

  __shared__ unsigned short As[128 * 32];
  __shared__ unsigned short Bs[128 * 32];

  const int tid = threadIdx.x;
  const int wid = tid >> 6;
  const int lane = tid & 63;

  const int sr0 = wid * 32 + (lane >> 2);
  const int sr1 = sr0 + 16;
  const int sc = (lane & 3) * 8;

  int ar0 = mt * 128 + sr0; if (ar0 >= n_e) ar0 = n_e - 1;
  int ar1 = mt * 128 + sr1; if (ar1 >= n_e) ar1 = n_e - 1;
  const unsigned short* ga0 = hbuf + (size_t)(row0 + ar0) * FFN + sc;
  const unsigned short* ga1 = hbuf + (size_t)(row0 + ar1) * FFN + sc;

  const unsigned short* gb0 = wdb + ((size_t)e * DIM + nt * 128 + sr0) * FFN + sc;
  const unsigned short* gb1 = wdb + ((size_t)e * DIM + nt * 128 + sr1) * FFN + sc;

  unsigned short* lA0 = &As[(wid * 32) * 32];
  unsigned short* lA1 = &As[(wid * 32 + 16) * 32];
  unsigned short* lB0 = &Bs[(wid * 32) * 32];
  unsigned short* lB1 = &Bs[(wid * 32 + 16) * 32];

  f32x4 acc[4][4];
#pragma unroll
  for (int i = 0; i < 4; ++i)
#pragma unroll
    for (int j = 0; j < 4; ++j) acc[i][j] = (f32x4){0.f, 0.f, 0.f, 0.f};

  const int wrow = (wid >> 1) * 64;
  const int wcol = (wid & 1) * 64;
  const int frow = lane & 15;
  const int fk = (lane >> 4) * 8;

  for (int k0 = 0; k0 < FFN; k0 += 32) {
    gload_lds16(ga0 + k0, lA0);
    gload_lds16(ga1 + k0, lA1);
    gload_lds16(gb0 + k0, lB0);
    gload_lds16(gb1 + k0, lB1);
    __syncthreads();
    bf16x8 af[4], bf[4];
#pragma unroll
    for (int i = 0; i < 4; ++i)
      af[i] = *reinterpret_cast<const bf16x8*>(&As[(wrow + i * 16 + frow) * 32 + fk]);
#pragma unroll
    for (int j = 0; j < 4; ++j)
      bf[j] = *reinterpret_cast<const bf16x8*>(&Bs[(wcol + j * 16 + frow) * 32 + fk]);
#pragma unroll
    for (int i = 0; i < 4; ++i)
#pragma unroll
      for (int j = 0; j < 4; ++j)
        acc[i][j] = __builtin_amdgcn_mfma_f32_16x16x32_bf16(af[i], bf[j], acc[i][j], 0, 0, 0);
    __syncthreads();
  }

#pragma unroll
  for (int i = 0; i < 4; ++i) {
#pragma unroll
    for (int jj = 0; jj < 4; ++jj) {
      int r = mt * 128 + wrow + i * 16 + (lane >> 4) * 4 + jj;
      if (r < n_e) {
        int tk = tok_list[row0 + r];
        float gt = gate_lst[row0 + r];
        int sl = slot_lst[row0 + r];
        float* yrow = yslots + ((size_t)sl * T_TOK + tk) * DIM;
#pragma unroll
        for (int j = 0; j < 4; ++j) {
          int d = nt * 128 + wcol + j * 16 + (lane & 15);
          yrow[d] = gt * acc[i][j][jj];
        }
      }
    }
  }
}

// ---------------- combine slots ----------------
__global__ void combine(const float* __restrict__ y, float* __restrict__ out) {
  int i = blockIdx.x * blockDim.x + threadIdx.x;
  int stride = gridDim.x * blockDim.x;
  const float4* y0 = reinterpret_cast<const float4*>(y);
  const float4* y1 = reinterpret_cast<const float4*>(y + (size_t)T_TOK * DIM);
  float4* o = reinterpret_cast<float4*>(out);
  for (; i < T_TOK * DIM / 4; i += stride) {
    float4 a = y0[i], b = y1[i];
    float4 r;
    r.x = a.x + b.x; r.y = a.y + b.y; r.z = a.z + b.z; r.w = a.w + b.w;
    o[i] = r;
  }
}

extern "C" void kernel_launch(void* const* d_in, const int* in_sizes, int n_in,
                              void* d_out, int out_size, void* d_ws, size_t ws_size,
                              hipStream_t stream) {
  const float* x = (const float*)d_in[0];
  const float* wr = (const float*)d_in[1];
  const float* wg = (const float*)d_in[2];
  const float* wu = (const float*)d_in[3];
  const float* wd = (const float*)d_in[4];
  float* out = (float*)d_out;

  char* ws = (char*)d_ws;
  size_t off = 0;
  auto alloc = [&](size_t bytes) {
    char* p = ws + off;
    off += (bytes + 255) & ~(size_t)255;
    return p;
  };
  unsigned short* xb   = (unsigned short*)alloc((size_t)T_TOK * DIM * 2);
  unsigned short* wgb  = (unsigned short*)alloc((size_t)NE * FFN * DIM * 2);
  unsigned short* wub  = (unsigned short*)alloc((size_t)NE * FFN * DIM * 2);
  unsigned short* wdb  = (unsigned short*)alloc((size_t)NE * DIM * FFN * 2);
  unsigned short* hbuf = (unsigned short*)alloc((size_t)T_TOK * 2 * FFN * 2);
  float* yslots        = (float*)alloc((size_t)2 * T_TOK * DIM * 4);
  int* top_i     = (int*)alloc(T_TOK * 2 * 4);
  float* top_g   = (float*)alloc(T_TOK * 2 * 4);
  int* tok_list  = (int*)alloc(T_TOK * 2 * 4);
  float* gate_lst = (float*)alloc(T_TOK * 2 * 4);
  int* slot_lst  = (int*)alloc(T_TOK * 2 * 4);
  int* offs      = (int*)alloc(64);
  int* cursor    = (int*)alloc(64);
  if (off > ws_size) return;  // diagnostic: all-zero output => ws too small

  cvt_f32_to_bf16<<<2048, 256, 0, stream>>>(x, xb, T_TOK * DIM / 4);
  cvt_f32_to_bf16<<<4096, 256, 0, stream>>>(wg, wgb, NE * FFN * DIM / 4);
  cvt_f32_to_bf16<<<4096, 256, 0, stream>>>(wu, wub, NE * FFN * DIM / 4);
  cvt_f32_to_bf16<<<4096, 256, 0, stream>>>(wd, wdb, NE * DIM * FFN / 4);
  router_topk<<<T_TOK / 4, 256, 0, stream>>>(x, wr, top_i, top_g);
  count_offsets<<<1, 256, 0, stream>>>(top_i, offs, cursor);
  scatter_tokens<<<(T_TOK + 255) / 256, 256, 0, stream>>>(top_i, top_g, cursor, tok_list,
                                                          gate_lst, slot_lst);
  gateup_gemm<<<dim3(FFN / 128, T_TOK / 128, NE), 256, 0, stream>>>(xb, wgb, wub, tok_list,
                                                                    offs, hbuf);
  down_gemm<<<dim3(DIM / 128, T_TOK / 128, NE), 256, 0, stream>>>(hbuf, wdb, tok_list, gate_lst,
                                                                  slot_lst, offs, yslots);
  combine<<<2048, 256, 0, stream>>>(yslots, out);
}

// Round 2
// 207.475 us; speedup vs baseline: 1.0932x; 1.0932x over previous
//
#include <hip/hip_runtime.h>
#include <hip/hip_bf16.h>

// Problem dims (fixed by reference): B=2,S=1024 -> T=2048 tokens
#define T_TOK 2048
#define DIM   2048   // D
#define FFN   1024   // F
#define NE    8      // experts
// top_k = 2 hardcoded

typedef __attribute__((ext_vector_type(8))) short bf16x8;
typedef __attribute__((ext_vector_type(4))) float f32x4;

__device__ __forceinline__ unsigned short f2bf(float f) {
  __hip_bfloat16 h = __float2bfloat16(f);
  return __builtin_bit_cast(unsigned short, h);
}

__device__ __forceinline__ void gload_lds16(const unsigned short* g, unsigned short* l) {
  __builtin_amdgcn_global_load_lds(
      (const __attribute__((address_space(1))) void*)g,
      (__attribute__((address_space(3))) void*)l, 16, 0, 0);
}

// ---------------- fp32 -> bf16 conversion (vectorized) ----------------
__global__ void cvt_f32_to_bf16(const float* __restrict__ in,
                                unsigned short* __restrict__ out, int n4) {
  int i = blockIdx.x * blockDim.x + threadIdx.x;
  int stride = gridDim.x * blockDim.x;
  for (; i < n4; i += stride) {
    float4 v = reinterpret_cast<const float4*>(in)[i];
    ushort4 o;
    o.x = f2bf(v.x); o.y = f2bf(v.y); o.z = f2bf(v.z); o.w = f2bf(v.w);
    reinterpret_cast<ushort4*>(out)[i] = o;
  }
}

// ---------------- router: logits + top2 + softmax gates ----------------
__global__ __launch_bounds__(256) void router_topk(
    const float* __restrict__ x, const float* __restrict__ wr,
    int* __restrict__ top_i, float* __restrict__ top_g) {
  int t = blockIdx.x * 4 + (threadIdx.x >> 6);
  int lane = threadIdx.x & 63;
  const float4* xr = reinterpret_cast<const float4*>(x) + (size_t)t * (DIM / 4);
  const float4* wrv = reinterpret_cast<const float4*>(wr);
  float acc[NE];
#pragma unroll
  for (int e = 0; e < NE; ++e) acc[e] = 0.f;
#pragma unroll
  for (int it = 0; it < DIM / 4 / 64; ++it) {
    int d4 = it * 64 + lane;
    float4 xv = xr[d4];
#pragma unroll
    for (int e = 0; e < NE; ++e) {
      float4 wv = wrv[e * (DIM / 4) + d4];
      acc[e] += xv.x * wv.x + xv.y * wv.y + xv.z * wv.z + xv.w * wv.w;
    }
  }
#pragma unroll
  for (int off = 32; off > 0; off >>= 1) {
#pragma unroll
    for (int e = 0; e < NE; ++e) acc[e] += __shfl_xor(acc[e], off, 64);
  }
  if (lane == 0) {
    int i0 = 0; float m0 = acc[0];
#pragma unroll
    for (int e = 1; e < NE; ++e) if (acc[e] > m0) { m0 = acc[e]; i0 = e; }
    int i1 = -1; float m1 = -3.4e38f;
#pragma unroll
    for (int e = 0; e < NE; ++e) if (e != i0 && acc[e] > m1) { m1 = acc[e]; i1 = e; }
    float tv = expf(m1 - m0);
    float den = 1.f + tv;
    top_i[t * 2 + 0] = i0; top_i[t * 2 + 1] = i1;
    top_g[t * 2 + 0] = 1.f / den; top_g[t * 2 + 1] = tv / den;
  }
}

// ---------------- count per expert + exclusive prefix offsets ----------------
__global__ void count_offsets(const int* __restrict__ top_i,
                              int* __restrict__ offs, int* __restrict__ cursor) {
  __shared__ int cnt[NE];
  if (threadIdx.x < NE) cnt[threadIdx.x] = 0;
  __syncthreads();
  for (int i = threadIdx.x; i < T_TOK * 2; i += blockDim.x) atomicAdd(&cnt[top_i[i]], 1);
  __syncthreads();
  if (threadIdx.x == 0) {
    int s = 0;
    for (int e = 0; e < NE; ++e) { offs[e] = s; cursor[e] = s; s += cnt[e]; }
    offs[NE] = s;
  }
}

// ---------------- scatter tokens into compact per-expert lists ----------------
__global__ void scatter_tokens(const int* __restrict__ top_i, const float* __restrict__ top_g,
                               int* __restrict__ cursor, int* __restrict__ tok_list,
                               float* __restrict__ gate_lst, int* __restrict__ slot_lst) {
  int t = blockIdx.x * blockDim.x + threadIdx.x;
  if (t >= T_TOK) return;
#pragma unroll
  for (int s = 0; s < 2; ++s) {
    int e = top_i[t * 2 + s];
    int p = atomicAdd(&cursor[e], 1);
    tok_list[p] = t;
    gate_lst[p] = top_g[t * 2 + s];
    slot_lst[p] = s;
  }
}

// ============ fused gate+up grouped GEMM: BM=64,BN=128,BK=64 ============
// LDS rows are 128B (64 bf16) = 8 x 16B chunks; chunk swizzle c ^= (row&7).
// Staging (1KB pass): lane -> row (l>>3), lds chunk (l&7), global chunk (l&7)^((l>>3)&7).
// Read: row key = lane&7 (row = 16*m + frow), chunk (kk*4 + (lane>>4)) ^ (lane&7).
__global__ __launch_bounds__(256, 2) void gateup_gemm(
    const unsigned short* __restrict__ xb, const unsigned short* __restrict__ wgb,
    const unsigned short* __restrict__ wub, const int* __restrict__ tok_list,
    const int* __restrict__ offs, unsigned short* __restrict__ hbuf) {
  const int e = blockIdx.z;
  const int row0 = offs[e];
  const int n_e = offs[e + 1] - row0;
  const int mt = blockIdx.y;
  if (mt * 64 >= n_e) return;
  const int nt = blockIdx.x;

  __shared__ unsigned short As[64 * 64];    // 8KB
  __shared__ unsigned short Bg[128 * 64];   // 16KB
  __shared__ unsigned short Bu[128 * 64];   // 16KB

  const int tid = threadIdx.x;
  const int wid = tid >> 6;
  const int lane = tid & 63;

  const int gchunk = (((lane & 7) ^ ((lane >> 3) & 7)) << 3);  // elem offset in row

  // A staging: 2 passes/wave, rows wid*16 + p*8 + (lane>>3)
  const unsigned short* gA[2];
  unsigned short* lA[2];
#pragma unroll
  for (int p = 0; p < 2; ++p) {
    int rt = wid * 16 + p * 8 + (lane >> 3);
    int ar = mt * 64 + rt; if (ar >= n_e) ar = n_e - 1;
    gA[p] = xb + (size_t)tok_list[row0 + ar] * DIM + gchunk;
    lA[p] = &As[(wid * 16 + p * 8) * 64];
  }
  // B staging: 4 passes/wave each matrix, rows wid*32 + p*8 + (lane>>3)
  const size_t wbase = (size_t)e * FFN * DIM + (size_t)(nt * 128) * DIM;
  const unsigned short* gG[4];
  const unsigned short* gU[4];
  unsigned short* lG[4];
  unsigned short* lU[4];
#pragma unroll
  for (int p = 0; p < 4; ++p) {
    int rt = wid * 32 + p * 8 + (lane >> 3);
    gG[p] = wgb + wbase + (size_t)rt * DIM + gchunk;
    gU[p] = wub + wbase + (size_t)rt * DIM + gchunk;
    lG[p] = &Bg[(wid * 32 + p * 8) * 64];
    lU[p] = &Bu[(wid * 32 + p * 8) * 64];
  }

  f32x4 accg[2][4];
  f32x4 accu[2][4];
#pragma unroll
  for (int i = 0; i < 2; ++i)
#pragma unroll
    for (int j = 0; j < 4; ++j) {
      accg[i][j] = (f32x4){0.f, 0.f, 0.f, 0.f};
      accu[i][j] = (f32x4){0.f, 0.f, 0.f, 0.f};
    }

  const int warow = (wid >> 1) * 32;
  const int wacol = (wid & 1) * 64;
  const int frow = lane & 15;
  // swizzled read element offsets for kk=0,1
  const int eo0 = ((((0 << 2) + (lane >> 4)) ^ (lane & 7)) << 3);
  const int eo1 = ((((1 << 2) + (lane >> 4)) ^ (lane & 7)) << 3);

  for (int k0 = 0; k0 < DIM; k0 += 64) {
#pragma unroll
    for (int p = 0; p < 2; ++p) gload_lds16(gA[p] + k0, lA[p]);
#pragma unroll
    for (int p = 0; p < 4; ++p) gload_lds16(gG[p] + k0, lG[p]);
#pragma unroll
    for (int p = 0; p < 4; ++p) gload_lds16(gU[p] + k0, lU[p]);
    __syncthreads();
#pragma unroll
    for (int kk = 0; kk < 2; ++kk) {
      const int eo = kk ? eo1 : eo0;
      bf16x8 af[2], bg[4], bu[4];
#pragma unroll
      for (int i = 0; i < 2; ++i)
        af[i] = *reinterpret_cast<const bf16x8*>(&As[(warow + i * 16 + frow) * 64 + eo]);
#pragma unroll
      for (int j = 0; j < 4; ++j) {
        bg[j] = *reinterpret_cast<const bf16x8*>(&Bg[(wacol + j * 16 + frow) * 64 + eo]);
        bu[j] = *reinterpret_cast<const bf16x8*>(&Bu[(wacol + j * 16 + frow) * 64 + eo]);
      }
#pragma unroll
      for (int i = 0; i < 2; ++i)
#pragma unroll
        for (int j = 0; j < 4; ++j) {
          accg[i][j] = __builtin_amdgcn_mfma_f32_16x16x32_bf16(af[i], bg[j], accg[i][j], 0, 0, 0);
          accu[i][j] = __builtin_amdgcn_mfma_f32_16x16x32_bf16(af[i], bu[j], accu[i][j], 0, 0, 0);
        }
    }
    __syncthreads();
  }

  // epilogue: h = silu(g)*u -> bf16
#pragma unroll
  for (int i = 0; i < 2; ++i) {
#pragma unroll
    for (int jj = 0; jj < 4; ++jj) {
      int r = mt * 64 + warow + i * 16 + (lane >> 4) * 4 + jj;
      if (r < n_e) {
#pragma unroll
        for (int j = 0; j < 4; ++j) {
          float g = accg[i][j][jj];
          float u = accu[i][j][jj];
          float h = (g / (1.f + __expf(-g))) * u;
          int f = nt * 128 + wacol + j * 16 + (lane & 15);
          hbuf[(size_t)(row0 + r) * FFN + f] = f2bf(h);
        }
      }
    }
  }
}

// ============ grouped down GEMM: BM=64,BN=128,BK=64 ============
__global__ __launch_bounds__(256, 4) void down_gemm(
    const unsigned short* __restrict__ hbuf, const unsigned short* __restrict__ wdb,
    const int* __restrict__ tok_list, const float* __restrict__ gate_lst,
    const int* __restrict__ slot_lst, const int* __restrict__ offs,
    float* __restrict__ yslots) {
  const int e = blockIdx.z;
  const int row0 = offs[e];
  const int n_e = offs[e + 1] - row0;
  const int mt = blockIdx.y;
  if (mt * 64 >= n_e) return;
  const int nt = blockIdx.x;  // D tile

  __shared__ unsigned short As[64 * 64];    // 8KB
  __shared__ unsigned short Bs[128 * 64];   // 16KB

  const int tid = threadIdx.x;
  const int wid = tid >> 6;
  const int lane = tid & 63;

  const int gchunk = (((lane & 7) ^ ((lane >> 3) & 7)) << 3);

  const unsigned short* gA[2];
  unsigned short* lA[2];
#pragma unroll
  for (int p = 0; p < 2; ++p) {
    int rt = wid * 16 + p * 8 + (lane >> 3);
    int ar = mt * 64 + rt; if (ar >= n_e) ar = n_e - 1;
    gA[p] = hbuf + (size_t)(row0 + ar) * FFN + gchunk;
    lA[p] = &As[(wid * 16 + p * 8) * 64];
  }
  const unsigned short* gB[4];
  unsigned short* lB[4];
#pragma unroll
  for (int p = 0; p < 4; ++p) {
    int rt = wid * 32 + p * 8 + (lane >> 3);
    gB[p] = wdb + ((size_t)e * DIM + nt * 128 + rt) * FFN + gchunk;
    lB[p] = &Bs[(wid * 32 + p * 8) * 64];
  }

  f32x4 acc[2][4];
#pragma unroll
  for (int i = 0; i < 2; ++i)
#pragma unroll
    for (int j = 0; j < 4; ++j) acc[i][j] = (f32x4){0.f, 0.f, 0.f, 0.f};

  const int warow = (wid >> 1) * 32;
  const int wacol = (wid & 1) * 64;
  const int frow = lane & 15;
  const int eo0 = ((((0 << 2) + (lane >> 4)) ^ (lane & 7)) << 3);
  const int eo1 = ((((1 << 2) + (lane >> 4)) ^ (lane & 7)) << 3);

  for (int k0 = 0; k0 < FFN; k0 += 64) {
#pragma unroll
    for (int p = 0; p < 2; ++p) gload_lds16(gA[p] + k0, lA[p]);
#pragma unroll
    for (int p = 0; p < 4; ++p) gload_lds16(gB[p] + k0, lB[p]);
    __syncthreads();
#pragma unroll
    for (int kk = 0; kk < 2; ++kk) {
      const int eo = kk ? eo1 : eo0;
      bf16x8 af[2], bf[4];
#pragma unroll
      for (int i = 0; i < 2; ++i)
        af[i] = *reinterpret_cast<const bf16x8*>(&As[(warow + i * 16 + frow) * 64 + eo]);
#pragma unroll
      for (int j = 0; j < 4; ++j)
        bf[j] = *reinterpret_cast<const bf16x8*>(&Bs[(wacol + j * 16 + frow) * 64 + eo]);
#pragma unroll
      for (int i = 0; i < 2; ++i)
#pragma unroll
        for (int j = 0; j < 4; ++j)
          acc[i][j] = __builtin_amdgcn_mfma_f32_16x16x32_bf16(af[i], bf[j], acc[i][j], 0, 0, 0);
    }
    __syncthreads();
  }

#pragma unroll
  for (int i = 0; i < 2; ++i) {
#pragma unroll
    for (int jj = 0; jj < 4; ++jj) {
      int r = mt * 64 + warow + i * 16 + (lane >> 4) * 4 + jj;
      if (r < n_e) {
        int tk = tok_list[row0 + r];
        float gt = gate_lst[row0 + r];
        int sl = slot_lst[row0 + r];
        float* yrow = yslots + ((size_t)sl * T_TOK + tk) * DIM;
#pragma unroll
        for (int j = 0; j < 4; ++j) {
          int d = nt * 128 + wacol + j * 16 + (lane & 15);
          yrow[d] = gt * acc[i][j][jj];
        }
      }
    }
  }
}

// ---------------- combine slots ----------------
__global__ void combine(const float* __restrict__ y, float* __restrict__ out) {
  int i = blockIdx.x * blockDim.x + threadIdx.x;
  int stride = gridDim.x * blockDim.x;
  const float4* y0 = reinterpret_cast<const float4*>(y);
  const float4* y1 = reinterpret_cast<const float4*>(y + (size_t)T_TOK * DIM);
  float4* o = reinterpret_cast<float4*>(out);
  for (; i < T_TOK * DIM / 4; i += stride) {
    float4 a = y0[i], b = y1[i];
    float4 r;
    r.x = a.x + b.x; r.y = a.y + b.y; r.z = a.z + b.z; r.w = a.w + b.w;
    o[i] = r;
  }
}

extern "C" void kernel_launch(void* const* d_in, const int* in_sizes, int n_in,
                              void* d_out, int out_size, void* d_ws, size_t ws_size,
                              hipStream_t stream) {
  const float* x = (const float*)d_in[0];
  const float* wr = (const float*)d_in[1];
  const float* wg = (const float*)d_in[2];
  const float* wu = (const float*)d_in[3];
  const float* wd = (const float*)d_in[4];
  float* out = (float*)d_out;

  char* ws = (char*)d_ws;
  size_t off = 0;
  auto alloc = [&](size_t bytes) {
    char* p = ws + off;
    off += (bytes + 255) & ~(size_t)255;
    return p;
  };
  unsigned short* xb   = (unsigned short*)alloc((size_t)T_TOK * DIM * 2);
  unsigned short* wgb  = (unsigned short*)alloc((size_t)NE * FFN * DIM * 2);
  unsigned short* wub  = (unsigned short*)alloc((size_t)NE * FFN * DIM * 2);
  unsigned short* wdb  = (unsigned short*)alloc((size_t)NE * DIM * FFN * 2);
  unsigned short* hbuf = (unsigned short*)alloc((size_t)T_TOK * 2 * FFN * 2);
  float* yslots        = (float*)alloc((size_t)2 * T_TOK * DIM * 4);
  int* top_i     = (int*)alloc(T_TOK * 2 * 4);
  float* top_g   = (float*)alloc(T_TOK * 2 * 4);
  int* tok_list  = (int*)alloc(T_TOK * 2 * 4);
  float* gate_lst = (float*)alloc(T_TOK * 2 * 4);
  int* slot_lst  = (int*)alloc(T_TOK * 2 * 4);
  int* offs      = (int*)alloc(64);
  int* cursor    = (int*)alloc(64);
  if (off > ws_size) return;

  cvt_f32_to_bf16<<<2048, 256, 0, stream>>>(x, xb, T_TOK * DIM / 4);
  cvt_f32_to_bf16<<<4096, 256, 0, stream>>>(wg, wgb, NE * FFN * DIM / 4);
  cvt_f32_to_bf16<<<4096, 256, 0, stream>>>(wu, wub, NE * FFN * DIM / 4);
  cvt_f32_to_bf16<<<4096, 256, 0, stream>>>(wd, wdb, NE * DIM * FFN / 4);
  router_topk<<<T_TOK / 4, 256, 0, stream>>>(x, wr, top_i, top_g);
  count_offsets<<<1, 256, 0, stream>>>(top_i, offs, cursor);
  scatter_tokens<<<(T_TOK + 255) / 256, 256, 0, stream>>>(top_i, top_g, cursor, tok_list,
                                                          gate_lst, slot_lst);
  // BM=64 tiles; grid.y covers worst-case n_e = T_TOK (2048/64 = 32)
  gateup_gemm<<<dim3(FFN / 128, 32, NE), 256, 0, stream>>>(xb, wgb, wub, tok_list, offs, hbuf);
  down_gemm<<<dim3(DIM / 128, 32, NE), 256, 0, stream>>>(hbuf, wdb, tok_list, gate_lst,
                                                         slot_lst, offs, yslots);
  combine<<<2048, 256, 0, stream>>>(yslots, out);
}